// Round 3
// baseline (25.162 us; speedup 1.0000x reference)
//
#include <hip/hip_runtime.h>

#define NBINS 256
#define BPS   32     // blocks per sample -> 128*32 = 4096 blocks (16/CU)
#define NT    256    // threads per block (4 waves)
#define NWAVE (NT / 64)

// ---------------- Kernel 1: per-block partial histograms ----------------
// grid = B * BPS blocks; each block histograms a contiguous chunk of one
// sample into wave-private LDS histograms, then writes its 256-bin partial
// histogram to d_ws with plain coalesced stores. Block 0 also zeroes d_out
// (stream-ordered before kernel 2's atomics -> replay-safe).
__global__ __launch_bounds__(NT) void hist_kernel(const float* __restrict__ x,
                                                  unsigned int* __restrict__ phist,
                                                  float* __restrict__ out,
                                                  int n_per_sample) {
    __shared__ unsigned int lh[NWAVE][NBINS];
    const int tid  = threadIdx.x;
    const int wave = tid >> 6;

    if (blockIdx.x == 0 && tid == 0) out[0] = 0.0f;

    for (int i = tid; i < NWAVE * NBINS; i += NT)
        ((unsigned int*)lh)[i] = 0u;
    __syncthreads();

    const int b     = blockIdx.x / BPS;
    const int blk   = blockIdx.x % BPS;
    const int chunk = n_per_sample / BPS;            // 196608/32 = 6144 (mult of 4*NT)
    const float4* src = (const float4*)(x + (size_t)b * n_per_sample
                                          + (size_t)blk * chunk);
    const int n4 = chunk >> 2;                       // 1536 float4 -> 6 iters/thread
    for (int i = tid; i < n4; i += NT) {
        float4 v = src[i];
        int i0 = (int)(v.x * 256.0f); i0 = min(max(i0, 0), NBINS - 1);
        int i1 = (int)(v.y * 256.0f); i1 = min(max(i1, 0), NBINS - 1);
        int i2 = (int)(v.z * 256.0f); i2 = min(max(i2, 0), NBINS - 1);
        int i3 = (int)(v.w * 256.0f); i3 = min(max(i3, 0), NBINS - 1);
        atomicAdd(&lh[wave][i0], 1u);
        atomicAdd(&lh[wave][i1], 1u);
        atomicAdd(&lh[wave][i2], 1u);
        atomicAdd(&lh[wave][i3], 1u);
    }
    __syncthreads();

    // merge waves -> plain store of this block's partial histogram
    unsigned int* dst = phist + (size_t)blockIdx.x * NBINS;
    for (int bin = tid; bin < NBINS; bin += NT) {
        unsigned int s = 0;
        #pragma unroll
        for (int w = 0; w < NWAVE; ++w) s += lh[w][bin];
        dst[bin] = s;
    }
}

// ---------------- Kernel 2: sum partials -> entropy -> MSE contribution ----------------
// grid = B blocks, NBINS threads; thread t owns bin t. Each block atomically
// accumulates (ent - target)^2 / B into d_out[0] (zeroed by kernel 1).
__global__ __launch_bounds__(NBINS) void entropy_kernel(const unsigned int* __restrict__ phist,
                                                        const float* __restrict__ target,
                                                        float* __restrict__ out,
                                                        float inv_n, float inv_b) {
    const int b   = blockIdx.x;
    const int tid = threadIdx.x;

    const unsigned int* base = phist + (size_t)b * BPS * NBINS;
    unsigned int h = 0;
    #pragma unroll
    for (int k = 0; k < BPS; ++k) h += base[k * NBINS + tid];

    float t = 0.0f;
    if (h > 0u) {
        float p = (float)h * inv_n;
        t = -p * log2f(p);
    }
    #pragma unroll
    for (int off = 32; off > 0; off >>= 1) t += __shfl_down(t, off, 64);
    __shared__ float ws[NBINS / 64];
    if ((tid & 63) == 0) ws[tid >> 6] = t;
    __syncthreads();
    if (tid == 0) {
        float ent = 0.0f;
        #pragma unroll
        for (int w = 0; w < NBINS / 64; ++w) ent += ws[w];
        float d = ent - target[b];
        atomicAdd(out, d * d * inv_b);
    }
}

extern "C" void kernel_launch(void* const* d_in, const int* in_sizes, int n_in,
                              void* d_out, int out_size, void* d_ws, size_t ws_size,
                              hipStream_t stream) {
    const float* x      = (const float*)d_in[0];
    const float* target = (const float*)d_in[1];
    float* out          = (float*)d_out;

    const int B = in_sizes[1];                 // 128
    const int N = in_sizes[0] / B;             // 196608

    unsigned int* phist = (unsigned int*)d_ws; // B*BPS*NBINS uints (4 MB)

    hist_kernel<<<B * BPS, NT, 0, stream>>>(x, phist, out, N);
    entropy_kernel<<<B, NBINS, 0, stream>>>(phist, target, out,
                                            1.0f / (float)N, 1.0f / (float)B);
}

// Round 4
// 24.856 us; speedup vs baseline: 1.0123x; 1.0123x over previous
//
#include <hip/hip_runtime.h>

#define NBINS 256
#define BPS   32     // blocks per sample -> 128*32 = 4096 blocks (16/CU)
#define NT    256    // threads per block (4 waves)
#define NWAVE (NT / 64)

// ---------------- Kernel 1: per-block partial histograms ----------------
// Templated on float4-count per block so the load loop fully unrolls:
// all loads issue before the LDS atomics -> max memory-level parallelism.
template<int N4>   // float4 elements per block (compile-time)
__global__ __launch_bounds__(NT) void hist_kernel_t(const float* __restrict__ x,
                                                    unsigned int* __restrict__ phist,
                                                    float* __restrict__ out) {
    __shared__ unsigned int lh[NWAVE][NBINS];
    const int tid  = threadIdx.x;
    const int wave = tid >> 6;

    if (blockIdx.x == 0 && tid == 0) out[0] = 0.0f;

    for (int i = tid; i < NWAVE * NBINS; i += NT)
        ((unsigned int*)lh)[i] = 0u;

    constexpr int ITER = N4 / NT;                    // 6 for N=196608, BPS=32
    const float4* src = (const float4*)x + (size_t)blockIdx.x * N4;

    // issue ALL loads first (independent, fully unrolled -> ~ITER*16B in flight/lane)
    float4 v[ITER];
    #pragma unroll
    for (int i = 0; i < ITER; ++i) v[i] = src[tid + i * NT];

    __syncthreads();   // lh zeroing complete (loads already in flight)

    #pragma unroll
    for (int i = 0; i < ITER; ++i) {
        int i0 = (int)(v[i].x * 256.0f); i0 = min(max(i0, 0), NBINS - 1);
        int i1 = (int)(v[i].y * 256.0f); i1 = min(max(i1, 0), NBINS - 1);
        int i2 = (int)(v[i].z * 256.0f); i2 = min(max(i2, 0), NBINS - 1);
        int i3 = (int)(v[i].w * 256.0f); i3 = min(max(i3, 0), NBINS - 1);
        atomicAdd(&lh[wave][i0], 1u);
        atomicAdd(&lh[wave][i1], 1u);
        atomicAdd(&lh[wave][i2], 1u);
        atomicAdd(&lh[wave][i3], 1u);
    }
    __syncthreads();

    unsigned int* dst = phist + (size_t)blockIdx.x * NBINS;
    for (int bin = tid; bin < NBINS; bin += NT) {
        unsigned int s = 0;
        #pragma unroll
        for (int w = 0; w < NWAVE; ++w) s += lh[w][bin];
        dst[bin] = s;
    }
}

// Generic fallback (runtime sizes) — same math, loop version.
__global__ __launch_bounds__(NT) void hist_kernel_g(const float* __restrict__ x,
                                                    unsigned int* __restrict__ phist,
                                                    float* __restrict__ out,
                                                    int n_per_sample) {
    __shared__ unsigned int lh[NWAVE][NBINS];
    const int tid  = threadIdx.x;
    const int wave = tid >> 6;
    if (blockIdx.x == 0 && tid == 0) out[0] = 0.0f;
    for (int i = tid; i < NWAVE * NBINS; i += NT)
        ((unsigned int*)lh)[i] = 0u;
    __syncthreads();
    const int b     = blockIdx.x / BPS;
    const int blk   = blockIdx.x % BPS;
    const int chunk = n_per_sample / BPS;
    const float4* src = (const float4*)(x + (size_t)b * n_per_sample
                                          + (size_t)blk * chunk);
    const int n4 = chunk >> 2;
    for (int i = tid; i < n4; i += NT) {
        float4 v = src[i];
        int i0 = (int)(v.x * 256.0f); i0 = min(max(i0, 0), NBINS - 1);
        int i1 = (int)(v.y * 256.0f); i1 = min(max(i1, 0), NBINS - 1);
        int i2 = (int)(v.z * 256.0f); i2 = min(max(i2, 0), NBINS - 1);
        int i3 = (int)(v.w * 256.0f); i3 = min(max(i3, 0), NBINS - 1);
        atomicAdd(&lh[wave][i0], 1u);
        atomicAdd(&lh[wave][i1], 1u);
        atomicAdd(&lh[wave][i2], 1u);
        atomicAdd(&lh[wave][i3], 1u);
    }
    __syncthreads();
    unsigned int* dst = phist + (size_t)blockIdx.x * NBINS;
    for (int bin = tid; bin < NBINS; bin += NT) {
        unsigned int s = 0;
        #pragma unroll
        for (int w = 0; w < NWAVE; ++w) s += lh[w][bin];
        dst[bin] = s;
    }
}

// ---------------- Kernel 2: sum partials -> entropy -> MSE contribution ----------------
__global__ __launch_bounds__(NBINS) void entropy_kernel(const unsigned int* __restrict__ phist,
                                                        const float* __restrict__ target,
                                                        float* __restrict__ out,
                                                        float inv_n, float inv_b) {
    const int b   = blockIdx.x;
    const int tid = threadIdx.x;

    const unsigned int* base = phist + (size_t)b * BPS * NBINS;
    unsigned int h = 0;
    #pragma unroll
    for (int k = 0; k < BPS; ++k) h += base[k * NBINS + tid];

    float t = 0.0f;
    if (h > 0u) {
        float p = (float)h * inv_n;
        t = -p * log2f(p);
    }
    #pragma unroll
    for (int off = 32; off > 0; off >>= 1) t += __shfl_down(t, off, 64);
    __shared__ float ws[NBINS / 64];
    if ((tid & 63) == 0) ws[tid >> 6] = t;
    __syncthreads();
    if (tid == 0) {
        float ent = 0.0f;
        #pragma unroll
        for (int w = 0; w < NBINS / 64; ++w) ent += ws[w];
        float d = ent - target[b];
        atomicAdd(out, d * d * inv_b);
    }
}

extern "C" void kernel_launch(void* const* d_in, const int* in_sizes, int n_in,
                              void* d_out, int out_size, void* d_ws, size_t ws_size,
                              hipStream_t stream) {
    const float* x      = (const float*)d_in[0];
    const float* target = (const float*)d_in[1];
    float* out          = (float*)d_out;

    const int B = in_sizes[1];                 // 128
    const int N = in_sizes[0] / B;             // 196608

    unsigned int* phist = (unsigned int*)d_ws; // B*BPS*NBINS uints (4 MB)

    if (N == 196608) {
        constexpr int N4 = (196608 / BPS) / 4; // 1536 float4 per block
        hist_kernel_t<N4><<<B * BPS, NT, 0, stream>>>(x, phist, out);
    } else {
        hist_kernel_g<<<B * BPS, NT, 0, stream>>>(x, phist, out, N);
    }
    entropy_kernel<<<B, NBINS, 0, stream>>>(phist, target, out,
                                            1.0f / (float)N, 1.0f / (float)B);
}

// Round 6
// 24.144 us; speedup vs baseline: 1.0422x; 1.0295x over previous
//
#include <hip/hip_runtime.h>

#define NBINS 256
#define BPS   32     // blocks per sample -> 128*32 = 4096 blocks
#define NT    256    // threads per block (4 waves)
#define NWAVE (NT / 64)

typedef float floatx4 __attribute__((ext_vector_type(4)));  // native vec for nt-load

// ---------------- Kernel 1: per-block partial histograms ----------------
// Compile-time trip count; all loads issued up front; nontemporal (streaming)
// reads so the 100 MB once-read input doesn't thrash per-XCD L2s.
template<int N4>   // float4 elements per block (compile-time)
__global__ __launch_bounds__(NT, 6) void hist_kernel_t(const float* __restrict__ x,
                                                       unsigned int* __restrict__ phist,
                                                       float* __restrict__ out) {
    __shared__ unsigned int lh[NWAVE][NBINS];
    const int tid  = threadIdx.x;
    const int wave = tid >> 6;

    if (blockIdx.x == 0 && tid == 0) out[0] = 0.0f;

    for (int i = tid; i < NWAVE * NBINS; i += NT)
        ((unsigned int*)lh)[i] = 0u;

    constexpr int ITER = N4 / NT;                    // 6 for N=196608, BPS=32
    const floatx4* src = (const floatx4*)x + (size_t)blockIdx.x * N4;

    // issue ALL loads first (independent, streaming/nontemporal)
    floatx4 v[ITER];
    #pragma unroll
    for (int i = 0; i < ITER; ++i)
        v[i] = __builtin_nontemporal_load(&src[tid + i * NT]);

    __syncthreads();   // lh zeroing complete (loads already in flight)

    #pragma unroll
    for (int i = 0; i < ITER; ++i) {
        // clamp on float side: min(v*256, 255); cvt-to-unsigned saturates
        // negatives to 0 -> identical to (int)(v*256) clipped to [0,255].
        unsigned int i0 = (unsigned int)fminf(v[i].x * 256.0f, 255.0f);
        unsigned int i1 = (unsigned int)fminf(v[i].y * 256.0f, 255.0f);
        unsigned int i2 = (unsigned int)fminf(v[i].z * 256.0f, 255.0f);
        unsigned int i3 = (unsigned int)fminf(v[i].w * 256.0f, 255.0f);
        atomicAdd(&lh[wave][i0], 1u);
        atomicAdd(&lh[wave][i1], 1u);
        atomicAdd(&lh[wave][i2], 1u);
        atomicAdd(&lh[wave][i3], 1u);
    }
    __syncthreads();

    unsigned int* dst = phist + (size_t)blockIdx.x * NBINS;
    for (int bin = tid; bin < NBINS; bin += NT) {
        unsigned int s = 0;
        #pragma unroll
        for (int w = 0; w < NWAVE; ++w) s += lh[w][bin];
        dst[bin] = s;
    }
}

// Generic fallback (runtime sizes) — same math, loop version.
__global__ __launch_bounds__(NT) void hist_kernel_g(const float* __restrict__ x,
                                                    unsigned int* __restrict__ phist,
                                                    float* __restrict__ out,
                                                    int n_per_sample) {
    __shared__ unsigned int lh[NWAVE][NBINS];
    const int tid  = threadIdx.x;
    const int wave = tid >> 6;
    if (blockIdx.x == 0 && tid == 0) out[0] = 0.0f;
    for (int i = tid; i < NWAVE * NBINS; i += NT)
        ((unsigned int*)lh)[i] = 0u;
    __syncthreads();
    const int b     = blockIdx.x / BPS;
    const int blk   = blockIdx.x % BPS;
    const int chunk = n_per_sample / BPS;
    const float4* src = (const float4*)(x + (size_t)b * n_per_sample
                                          + (size_t)blk * chunk);
    const int n4 = chunk >> 2;
    for (int i = tid; i < n4; i += NT) {
        float4 v = src[i];
        unsigned int i0 = (unsigned int)fminf(v.x * 256.0f, 255.0f);
        unsigned int i1 = (unsigned int)fminf(v.y * 256.0f, 255.0f);
        unsigned int i2 = (unsigned int)fminf(v.z * 256.0f, 255.0f);
        unsigned int i3 = (unsigned int)fminf(v.w * 256.0f, 255.0f);
        atomicAdd(&lh[wave][i0], 1u);
        atomicAdd(&lh[wave][i1], 1u);
        atomicAdd(&lh[wave][i2], 1u);
        atomicAdd(&lh[wave][i3], 1u);
    }
    __syncthreads();
    unsigned int* dst = phist + (size_t)blockIdx.x * NBINS;
    for (int bin = tid; bin < NBINS; bin += NT) {
        unsigned int s = 0;
        #pragma unroll
        for (int w = 0; w < NWAVE; ++w) s += lh[w][bin];
        dst[bin] = s;
    }
}

// ---------------- Kernel 2: sum partials -> entropy -> MSE contribution ----------------
__global__ __launch_bounds__(NBINS) void entropy_kernel(const unsigned int* __restrict__ phist,
                                                        const float* __restrict__ target,
                                                        float* __restrict__ out,
                                                        float inv_n, float inv_b) {
    const int b   = blockIdx.x;
    const int tid = threadIdx.x;

    const unsigned int* base = phist + (size_t)b * BPS * NBINS;
    unsigned int h = 0;
    #pragma unroll
    for (int k = 0; k < BPS; ++k) h += base[k * NBINS + tid];

    float t = 0.0f;
    if (h > 0u) {
        float p = (float)h * inv_n;
        t = -p * log2f(p);
    }
    #pragma unroll
    for (int off = 32; off > 0; off >>= 1) t += __shfl_down(t, off, 64);
    __shared__ float ws[NBINS / 64];
    if ((tid & 63) == 0) ws[tid >> 6] = t;
    __syncthreads();
    if (tid == 0) {
        float ent = 0.0f;
        #pragma unroll
        for (int w = 0; w < NBINS / 64; ++w) ent += ws[w];
        float d = ent - target[b];
        atomicAdd(out, d * d * inv_b);
    }
}

extern "C" void kernel_launch(void* const* d_in, const int* in_sizes, int n_in,
                              void* d_out, int out_size, void* d_ws, size_t ws_size,
                              hipStream_t stream) {
    const float* x      = (const float*)d_in[0];
    const float* target = (const float*)d_in[1];
    float* out          = (float*)d_out;

    const int B = in_sizes[1];                 // 128
    const int N = in_sizes[0] / B;             // 196608

    unsigned int* phist = (unsigned int*)d_ws; // B*BPS*NBINS uints (4 MB)

    if (N == 196608) {
        constexpr int N4 = (196608 / BPS) / 4; // 1536 float4 per block
        hist_kernel_t<N4><<<B * BPS, NT, 0, stream>>>(x, phist, out);
    } else {
        hist_kernel_g<<<B * BPS, NT, 0, stream>>>(x, phist, out, N);
    }
    entropy_kernel<<<B, NBINS, 0, stream>>>(phist, target, out,
                                            1.0f / (float)N, 1.0f / (float)B);
}